// Round 1
// 191.592 us; speedup vs baseline: 1.2345x; 1.2345x over previous
//
#include <hip/hip_runtime.h>
#include <hip/hip_bf16.h>

// MaskedAttention: out = softmax(tril(q k^T)) v, q/k/v = x @ W{q,k,v}
// B=8 T=2048 D=1024 H=64, fp32 in/out, no 1/sqrt(H) scaling.
//
// Precision plan: q,k projections and QK^T use hi/lo bf16 splitting
// (3-MFMA "bf16x3") so logits are ~fp32-accurate; V/P plain bf16.

typedef __bf16 bf16x8 __attribute__((ext_vector_type(8)));
typedef float f32x4 __attribute__((ext_vector_type(4)));

#define MFMA16(a, b, c) __builtin_amdgcn_mfma_f32_16x16x32_bf16((a), (b), (c), 0, 0, 0)

static constexpr int BB = 8;
static constexpr int TT = 2048;
static constexpr int DD = 1024;
static constexpr int HH = 64;
static constexpr int NROW = BB * TT;       // 16384
static constexpr int WELEM = DD * HH;      // 65536 per matrix

__device__ __forceinline__ float rmax16(float v) {
#pragma unroll
  for (int m = 1; m < 16; m <<= 1) v = fmaxf(v, __shfl_xor(v, m, 64));
  return v;
}
__device__ __forceinline__ float rsum16(float v) {
#pragma unroll
  for (int m = 1; m < 16; m <<= 1) v += __shfl_xor(v, m, 64);
  return v;
}

// ---------------------------------------------------------------- W prep ---
// W [1024][64] fp32 -> Wt hi/lo [3][64][1024] bf16 (transposed, split)
__global__ __launch_bounds__(256) void wprep_kernel(
    const float* __restrict__ Wq, const float* __restrict__ Wk,
    const float* __restrict__ Wv, __bf16* __restrict__ WtHi,
    __bf16* __restrict__ WtLo) {
  int tid = blockIdx.x * 256 + threadIdx.x;
  if (tid >= 3 * WELEM) return;
  int m = tid / WELEM;
  int rem = tid - m * WELEM;
  int d = rem >> 6;
  int h = rem & 63;
  const float* W = (m == 0) ? Wq : ((m == 1) ? Wk : Wv);
  float v = W[d * 64 + h];
  __bf16 hi = (__bf16)v;
  float lo = v - (float)hi;
  size_t o = (size_t)m * WELEM + (size_t)h * 1024 + d;
  WtHi[o] = hi;
  WtLo[o] = (__bf16)lo;
}

// ------------------------------------------------------------ projection ---
// Fused x->bf16(hi/lo) conversion + GEMM. Each wave: 16 rows x 64 cols x K=1024.
// q,k: 3-MFMA split (accurate); v: hi-only. Writes qh/ql/kh/kl [16384][64],
// vt [8][64][2048] (transposed for PV B-fragments).
__global__ __launch_bounds__(256) void proj_kernel(
    const float* __restrict__ x, const __bf16* __restrict__ WtHi,
    const __bf16* __restrict__ WtLo, __bf16* __restrict__ qh,
    __bf16* __restrict__ ql, __bf16* __restrict__ kh,
    __bf16* __restrict__ kl, __bf16* __restrict__ vt) {
  const int w = threadIdx.x >> 6, l = threadIdx.x & 63;
  const int lr = l & 15, lg = l >> 4;
  const int rt = blockIdx.x * 4 + w;
  const int r0 = rt * 16;

  const float* xp = x + (size_t)(r0 + lr) * DD + lg * 8;
  const __bf16* wq_h = WtHi;
  const __bf16* wk_h = WtHi + WELEM;
  const __bf16* wv_h = WtHi + 2 * WELEM;
  const __bf16* wq_l = WtLo;
  const __bf16* wk_l = WtLo + WELEM;

  f32x4 aq[4], ak[4], av[4];
#pragma unroll
  for (int c = 0; c < 4; ++c) {
    aq[c] = (f32x4){0.f, 0.f, 0.f, 0.f};
    ak[c] = (f32x4){0.f, 0.f, 0.f, 0.f};
    av[c] = (f32x4){0.f, 0.f, 0.f, 0.f};
  }

  for (int d0 = 0; d0 < DD; d0 += 32) {
    const float4 xa = *(const float4*)(xp + d0);
    const float4 xb = *(const float4*)(xp + d0 + 4);
    float xs[8] = {xa.x, xa.y, xa.z, xa.w, xb.x, xb.y, xb.z, xb.w};
    bf16x8 ah, al;
#pragma unroll
    for (int j = 0; j < 8; ++j) {
      __bf16 h = (__bf16)xs[j];
      ah[j] = h;
      al[j] = (__bf16)(xs[j] - (float)h);
    }
#pragma unroll
    for (int c = 0; c < 4; ++c) {
      const int wo = (c * 16 + lr) * 1024 + d0 + lg * 8;
      bf16x8 bqh = *(const bf16x8*)(wq_h + wo);
      bf16x8 bql = *(const bf16x8*)(wq_l + wo);
      bf16x8 bkh = *(const bf16x8*)(wk_h + wo);
      bf16x8 bkl = *(const bf16x8*)(wk_l + wo);
      bf16x8 bvh = *(const bf16x8*)(wv_h + wo);
      aq[c] = MFMA16(ah, bqh, aq[c]);
      aq[c] = MFMA16(ah, bql, aq[c]);
      aq[c] = MFMA16(al, bqh, aq[c]);
      ak[c] = MFMA16(ah, bkh, ak[c]);
      ak[c] = MFMA16(ah, bkl, ak[c]);
      ak[c] = MFMA16(al, bkh, ak[c]);
      av[c] = MFMA16(ah, bvh, av[c]);
    }
  }

#pragma unroll
  for (int c = 0; c < 4; ++c) {
#pragma unroll
    for (int i = 0; i < 4; ++i) {
      const int row = r0 + lg * 4 + i;  // C-layout: row=(lane>>4)*4+reg
      const int col = c * 16 + lr;      //           col=lane&15
      const size_t oq = (size_t)row * 64 + col;
      float qv = aq[c][i];
      __bf16 qhi = (__bf16)qv;
      qh[oq] = qhi;
      ql[oq] = (__bf16)(qv - (float)qhi);
      float kv = ak[c][i];
      __bf16 khi = (__bf16)kv;
      kh[oq] = khi;
      kl[oq] = (__bf16)(kv - (float)khi);
      const int bb = row >> 11, tt = row & 2047;
      vt[((size_t)bb * 64 + col) * 2048 + tt] = (__bf16)av[c][i];
    }
  }
}

// -------------------------------------------------------------- attention ---
// Split-K flash. One block (4 waves) per 16-row q-tile; waves stride over
// 32-key tiles with private online-softmax state, then LSE-merge via LDS.
// 32-key tiles: QK^T = 3-term split (6 MFMA), fp32 online softmax via 16-lane
// shuffles, P staged bf16 in padded LDS (80B rows), PV = 4 MFMA.
__global__ __launch_bounds__(256) void attn_kernel(
    const __bf16* __restrict__ qh, const __bf16* __restrict__ ql,
    const __bf16* __restrict__ kh, const __bf16* __restrict__ kl,
    const __bf16* __restrict__ vt, float* __restrict__ out) {
  __shared__ __bf16 P[4][16][40];   // 40-col pad: 80B rows -> conflict-free b128
  __shared__ float Sm[4][16];       // per-wave row maxes
  __shared__ float Sl[4][16];       // per-wave row sums
  __shared__ float OB[4][16][68];   // per-wave scaled O (68 pad: <=2-way, free)
  __shared__ float Dinv[16];        // 1/denom per row
  const int w = threadIdx.x >> 6, l = threadIdx.x & 63;
  const int lr = l & 15, lg = l >> 4;
  const int b = blockIdx.y;
  const int qt = 127 - blockIdx.x;  // heavy tiles first (tail shrink)
  const int q0 = qt * 16;
  const float NEG = -__builtin_inff();

  const size_t qb = ((size_t)b * TT + q0 + lr) * 64 + lg * 8;
  const bf16x8 fqh0 = *(const bf16x8*)(qh + qb);
  const bf16x8 fqh1 = *(const bf16x8*)(qh + qb + 32);
  const bf16x8 fql0 = *(const bf16x8*)(ql + qb);
  const bf16x8 fql1 = *(const bf16x8*)(ql + qb + 32);

  f32x4 o0 = {0.f, 0.f, 0.f, 0.f}, o1 = o0, o2 = o0, o3 = o0;
  float m[4] = {NEG, NEG, NEG, NEG};
  float su[4] = {0.f, 0.f, 0.f, 0.f};
  const int nkt = (q0 + 47) >> 5;  // ceil((q0+16)/32)

#pragma unroll 1
  for (int kt = w; kt < nkt; kt += 4) {
    const int j0 = kt * 32;
    const f32x4 z = {0.f, 0.f, 0.f, 0.f};
    f32x4 sa, sb = {NEG, NEG, NEG, NEG};
    {
      const size_t kb = ((size_t)b * TT + j0 + lr) * 64 + lg * 8;
      const bf16x8 fk0 = *(const bf16x8*)(kh + kb);
      const bf16x8 fk1 = *(const bf16x8*)(kh + kb + 32);
      const bf16x8 fl0 = *(const bf16x8*)(kl + kb);
      const bf16x8 fl1 = *(const bf16x8*)(kl + kb + 32);
      f32x4 c0 = MFMA16(fqh1, fk1, MFMA16(fqh0, fk0, z));
      f32x4 c1 = MFMA16(fqh1, fl1, MFMA16(fqh0, fl0, z));
      f32x4 c2 = MFMA16(fql1, fk1, MFMA16(fql0, fk0, z));
      sa = c0 + c1 + c2;
    }
    const bool haveB = (j0 + 16) <= (q0 + 15);
    if (haveB) {
      const size_t kb = ((size_t)b * TT + j0 + 16 + lr) * 64 + lg * 8;
      const bf16x8 fk0 = *(const bf16x8*)(kh + kb);
      const bf16x8 fk1 = *(const bf16x8*)(kh + kb + 32);
      const bf16x8 fl0 = *(const bf16x8*)(kl + kb);
      const bf16x8 fl1 = *(const bf16x8*)(kl + kb + 32);
      f32x4 c0 = MFMA16(fqh1, fk1, MFMA16(fqh0, fk0, z));
      f32x4 c1 = MFMA16(fqh1, fl1, MFMA16(fqh0, fl0, z));
      f32x4 c2 = MFMA16(fql1, fk1, MFMA16(fql0, fk0, z));
      sb = c0 + c1 + c2;
    }
    // causal mask (row = q0 + lg*4 + i, key = j0 [+16] + lr)
#pragma unroll
    for (int i = 0; i < 4; ++i) {
      const int rowg = q0 + lg * 4 + i;
      if (j0 + lr > rowg) sa[i] = NEG;
      if (j0 + 16 + lr > rowg) sb[i] = NEG;
    }
    // online softmax update + stage P in LDS
#pragma unroll
    for (int i = 0; i < 4; ++i) {
      float t = rmax16(fmaxf(sa[i], sb[i]));
      const float mn = fmaxf(m[i], t);
      const float sc = __expf(m[i] - mn);
      m[i] = mn;
      const float pa = __expf(sa[i] - mn);
      const float pb = __expf(sb[i] - mn);
      su[i] = su[i] * sc + rsum16(pa + pb);
      o0[i] *= sc; o1[i] *= sc; o2[i] *= sc; o3[i] *= sc;
      P[w][lg * 4 + i][lr] = (__bf16)pa;
      P[w][lg * 4 + i][16 + lr] = (__bf16)pb;
    }
    // PV: A-frag of P (same-wave LDS ops are in-order; compiler adds waits)
    const bf16x8 pf = *(const bf16x8*)(&P[w][lr][lg * 8]);
    const size_t vb = ((size_t)b * 64 + lr) * 2048 + j0 + lg * 8;
    o0 = MFMA16(pf, *(const bf16x8*)(vt + vb), o0);
    o1 = MFMA16(pf, *(const bf16x8*)(vt + vb + (size_t)16 * 2048), o1);
    o2 = MFMA16(pf, *(const bf16x8*)(vt + vb + (size_t)32 * 2048), o2);
    o3 = MFMA16(pf, *(const bf16x8*)(vt + vb + (size_t)48 * 2048), o3);
  }

  // ------- LSE merge of the 4 per-wave partials -------
  if (lr == 0) {
#pragma unroll
    for (int i = 0; i < 4; ++i) {
      Sm[w][lg * 4 + i] = m[i];
      Sl[w][lg * 4 + i] = su[i];
    }
  }
  __syncthreads();
#pragma unroll
  for (int i = 0; i < 4; ++i) {
    const int row = lg * 4 + i;
    float M = fmaxf(fmaxf(Sm[0][row], Sm[1][row]),
                    fmaxf(Sm[2][row], Sm[3][row]));
    const float sc = __expf(m[i] - M);  // 0 if this wave was idle (m=-inf)
    OB[w][row][lr] = o0[i] * sc;
    OB[w][row][16 + lr] = o1[i] * sc;
    OB[w][row][32 + lr] = o2[i] * sc;
    OB[w][row][48 + lr] = o3[i] * sc;
    if (w == 0 && lr == 0) {
      float denom = 0.f;
#pragma unroll
      for (int w2 = 0; w2 < 4; ++w2)
        denom += Sl[w2][row] * __expf(Sm[w2][row] - M);
      Dinv[row] = 1.0f / denom;
    }
  }
  __syncthreads();
  const int t = threadIdx.x;
#pragma unroll
  for (int k2 = 0; k2 < 4; ++k2) {
    const int e = t + 256 * k2;
    const int row = e >> 6, col = e & 63;
    const float s = OB[0][row][col] + OB[1][row][col] + OB[2][row][col] +
                    OB[3][row][col];
    out[((size_t)b * TT + q0 + row) * 64 + col] = s * Dinv[row];
  }
}

// ------------------------------------------------------------------ launch ---
extern "C" void kernel_launch(void* const* d_in, const int* in_sizes, int n_in,
                              void* d_out, int out_size, void* d_ws,
                              size_t ws_size, hipStream_t stream) {
  const float* x = (const float*)d_in[0];
  const float* Wq = (const float*)d_in[1];
  const float* Wk = (const float*)d_in[2];
  const float* Wv = (const float*)d_in[3];
  float* out = (float*)d_out;
  char* ws = (char*)d_ws;

  size_t off = 0;
  __bf16* WtHi = (__bf16*)(ws + off); off += (size_t)3 * WELEM * 2;
  __bf16* WtLo = (__bf16*)(ws + off); off += (size_t)3 * WELEM * 2;
  __bf16* qh = (__bf16*)(ws + off); off += (size_t)NROW * 64 * 2;
  __bf16* ql = (__bf16*)(ws + off); off += (size_t)NROW * 64 * 2;
  __bf16* kh = (__bf16*)(ws + off); off += (size_t)NROW * 64 * 2;
  __bf16* kl = (__bf16*)(ws + off); off += (size_t)NROW * 64 * 2;
  __bf16* vt = (__bf16*)(ws + off); off += (size_t)NROW * 64 * 2;  // ~10.8 MB

  wprep_kernel<<<dim3((3 * WELEM + 255) / 256), dim3(256), 0, stream>>>(
      Wq, Wk, Wv, WtHi, WtLo);
  proj_kernel<<<dim3(NROW / 64), dim3(256), 0, stream>>>(
      x, WtHi, WtLo, qh, ql, kh, kl, vt);
  attn_kernel<<<dim3(128, BB), dim3(256), 0, stream>>>(
      qh, ql, kh, kl, vt, out);
}